// Round 14
// baseline (398.922 us; speedup 1.0000x reference)
//
#include <hip/hip_runtime.h>

#define BB 32
#define HH 384
#define WW 1280
#define KS 9
#define NT 256                       // 4 waves per block
#define NPAIR 192                    // row-pairs per column
#define BSTR ((size_t)WW * NPAIR)    // f2v per batch

typedef float f2v __attribute__((ext_vector_type(2)));
typedef float4 f4;

static __device__ __forceinline__ f2v pk_mul(f2v a, f2v b) {
    f2v d; asm("v_pk_mul_f32 %0, %1, %2" : "=v"(d) : "v"(a), "v"(b)); return d;
}
static __device__ __forceinline__ f2v pk_fma(f2v a, f2v b, f2v c) {
    f2v d; asm("v_pk_fma_f32 %0, %1, %2, %3" : "=v"(d) : "v"(a), "v"(b), "v"(c)); return d;
}
// DPP wave shifts; bound_ctrl=true zero-fills edge lanes (verified rounds 2-13)
static __device__ __forceinline__ float du(float v) {
    return __int_as_float(__builtin_amdgcn_mov_dpp(__float_as_int(v), 0x138, 0xf, 0xf, true));
}
static __device__ __forceinline__ float dd(float v) {
    return __int_as_float(__builtin_amdgcn_mov_dpp(__float_as_int(v), 0x130, 0xf, 0xf, true));
}
static __device__ __forceinline__ f2v du2(f2v v) { f2v r; r.x = du(v.x); r.y = du(v.y); return r; }
static __device__ __forceinline__ f2v dd2(f2v v) { f2v r; r.x = dd(v.x); r.y = dd(v.y); return r; }
template<int U> __device__ __forceinline__ void setc(f4& q, float v) {
    if constexpr (U == 0) q.x = v;
    else if constexpr (U == 1) q.y = v;
    else if constexpr (U == 2) q.z = v;
    else q.w = v;
}

// ---------------------------------------------------------------------------
// Transpose: x[b][h][w] -> xq[b][col][pair] f2v, pair p = (row 2p, row 2p+1)
// ---------------------------------------------------------------------------
__global__ __launch_bounds__(512) void scnn_tr(const float* __restrict__ x,
                                               f2v* __restrict__ xq) {
    __shared__ float tile[HH][33];
    const int b = blockIdx.y;
    const int c0 = blockIdx.x * 32;
    const int t = threadIdx.x;
    const int col = t & 31;
    const int r0 = t >> 5;
    const float* xb = x + (size_t)b * HH * WW + c0;
#pragma unroll
    for (int k = 0; k < 24; ++k) {
        const int r = r0 + 16 * k;
        tile[r][col] = xb[(size_t)r * WW + col];
    }
    __syncthreads();
    f2v* xqb = xq + (size_t)b * BSTR + (size_t)c0 * NPAIR;
#pragma unroll
    for (int i = 0; i < 12; ++i) {
        const int idx = i * 512 + t;
        const int cl = idx / NPAIR;
        const int pp = idx - cl * NPAIR;
        f2v v;
        v.x = tile[2 * pp][cl];
        v.y = tile[2 * pp + 1][cl];
        xqb[(size_t)cl * NPAIR + pp] = v;
    }
}

// fallback-path copy: finals (ws, [b][h][w]) -> d_out
__global__ __launch_bounds__(256) void scnn_cp(const f4* __restrict__ s,
                                               f4* __restrict__ d, int n) {
    int i = blockIdx.x * 256 + threadIdx.x;
    const int stride = gridDim.x * 256;
    for (; i < n; i += stride) d[i] = s[i];
}

// 9-tap correlation + ReLU for ONE pair whose window is pairs C0..C4
// (C2 = the pair itself). Even taps packed, odd taps scalar on halves.
static __device__ __forceinline__ f2v conv5(f2v C0, f2v C1, f2v C2, f2v C3, f2v C4,
                                            const f2v (&W)[KS]) {
    f2v a = pk_mul(W[0], C0);
    a = pk_fma(W[2], C1, a);
    a = pk_fma(W[4], C2, a);
    a = pk_fma(W[6], C3, a);
    a = pk_fma(W[8], C4, a);
    float ax = a.x, ay = a.y;
    ax = fmaf(W[1].x, C0.y, ax);
    ax = fmaf(W[3].x, C1.y, ax);
    ax = fmaf(W[5].x, C2.y, ax);
    ax = fmaf(W[7].x, C3.y, ax);
    ay = fmaf(W[1].x, C1.x, ay);
    ay = fmaf(W[3].x, C2.x, ay);
    ay = fmaf(W[5].x, C3.x, ay);
    ay = fmaf(W[7].x, C4.x, ay);
    f2v r; r.x = fmaxf(ax, 0.f); r.y = fmaxf(ay, 0.f);
    return r;
}

// 4 waves/batch, 2 pairs/lane (128 slots/wave, owns 48, 40-pair halo each side
// -> 20 steps per state-only LDS refresh). x and out1 live in SEPARATE buffers
// so every lane (halo included) reads pristine x/out1 straight from global.
__global__ __launch_bounds__(NT, 1) void scnn_scan(const f2v* __restrict__ xq,
                                                   f2v* __restrict__ o1,
                                                   float* __restrict__ fin,
                                                   const float* __restrict__ w_lr,
                                                   const float* __restrict__ w_rl) {
    __shared__ float lbx[2][NPAIR], lby[2][NPAIR];

    const int b   = blockIdx.x;
    const int tid = threadIdx.x;
    const int wid = tid >> 6;
    const int l   = tid & 63;
    const int p0  = 48 * wid - 40 + 2 * l;   // this lane's even pair (may be OOB)
    const int p1  = p0 + 1;
    const bool inb0 = (p0 >= 0) && (p0 < NPAIR);
    const bool inb1 = (p1 >= 0) && (p1 < NPAIR);
    const bool owned = (l >= 20) && (l < 44);
    const int p0x = p0 < 0 ? 0 : (p0 > NPAIR - 2 ? NPAIR - 2 : p0);  // even clamp
    const int p1x = p0x + 1;
    const int R0 = 2 * p0;                    // first owned row (owned lanes)

    const f2v* xqb = xq + (size_t)b * BSTR;
    f2v*       o1b = o1 + (size_t)b * BSTR;
    float*     finb = fin + (size_t)b * HH * WW;

    f2v Wl[KS], Wr[KS];
#pragma unroll
    for (int k = 0; k < KS; ++k) {
        const float a = w_lr[k], c = w_rl[k];
        Wl[k].x = a; Wl[k].y = a;
        Wr[k].x = c; Wr[k].y = c;
    }

    int par = 0;
    f2v S0, S1;
    f4 XR[10];

#define REFRESH() do { \
    if (owned) { lbx[par][p0] = S0.x; lby[par][p0] = S0.y; \
                 lbx[par][p1] = S1.x; lby[par][p1] = S1.y; } \
    asm volatile("s_waitcnt lgkmcnt(0)\n\ts_barrier" ::: "memory"); \
    { float a0 = lbx[par][p0x], b0 = lby[par][p0x]; \
      float a1 = lbx[par][p1x], b1 = lby[par][p1x]; \
      S0.x = inb0 ? a0 : 0.f; S0.y = inb0 ? b0 : 0.f; \
      S1.x = inb1 ? a1 : 0.f; S1.y = inb1 ? b1 : 0.f; } \
    par ^= 1; \
} while (0)

    // ======================= PASS 1 (left -> right) =======================
#define STEP1(COL, XI) do { \
    f2v U0 = du2(S0), U1 = du2(S1), D0 = dd2(S0), D1 = dd2(S1); \
    f2v A0 = conv5(U0, U1, S0, S1, D0, Wl); \
    f2v A1 = conv5(U1, S0, S1, D0, D1, Wl); \
    f4 xv = XR[XI]; \
    S0.x = inb0 ? (xv.x + A0.x) : 0.f;  S0.y = inb0 ? (xv.y + A0.y) : 0.f; \
    S1.x = inb1 ? (xv.z + A1.x) : 0.f;  S1.y = inb1 ? (xv.w + A1.y) : 0.f; \
    if (owned) { f4 sv; sv.x = S0.x; sv.y = S0.y; sv.z = S1.x; sv.w = S1.y; \
        *(f4*)(o1b + (size_t)(COL) * NPAIR + p0) = sv; } \
    { const int _pc = (COL) + 10 > WW - 1 ? WW - 1 : (COL) + 10; \
      XR[XI] = *(const f4*)(xqb + (size_t)_pc * NPAIR + p0x); } \
} while (0)

    {
        f4 v = *(const f4*)(xqb + p0x);   // col 0: out1[0] = x[0]
        S0.x = inb0 ? v.x : 0.f; S0.y = inb0 ? v.y : 0.f;
        S1.x = inb1 ? v.z : 0.f; S1.y = inb1 ? v.w : 0.f;
        if (owned) { f4 sv; sv.x = S0.x; sv.y = S0.y; sv.z = S1.x; sv.w = S1.y;
            *(f4*)(o1b + p0) = sv; }
#pragma unroll
        for (int i = 0; i < 10; ++i)
            XR[i] = *(const f4*)(xqb + (size_t)(1 + i) * NPAIR + p0x);
#pragma unroll 1
        for (int g = 0; g < 127; ++g) {
            if ((g & 1) == 0) REFRESH();
            const int c0 = 1 + 10 * g;
            STEP1(c0 + 0, 0); STEP1(c0 + 1, 1); STEP1(c0 + 2, 2); STEP1(c0 + 3, 3);
            STEP1(c0 + 4, 4); STEP1(c0 + 5, 5); STEP1(c0 + 6, 6); STEP1(c0 + 7, 7);
            STEP1(c0 + 8, 8); STEP1(c0 + 9, 9);
        }
        // tail: cols 1271..1279 (refresh at g=126 covers 10+9=19 <= 20 steps)
        STEP1(1271, 0); STEP1(1272, 1); STEP1(1273, 2); STEP1(1274, 3);
        STEP1(1275, 4); STEP1(1276, 5); STEP1(1277, 6); STEP1(1278, 7);
        STEP1(1279, 8);
    }

    __syncthreads();   // full drain: pass-1 o1 stores visible to all waves

    // ======================= PASS 2 (right -> left) =======================
    {
        f4 ob[4];

#define STEP2(COL, XI, WPOS) do { \
    f2v U0 = du2(S0), U1 = du2(S1), D0 = dd2(S0), D1 = dd2(S1); \
    f2v A0 = conv5(U0, U1, S0, S1, D0, Wr); \
    f2v A1 = conv5(U1, S0, S1, D0, D1, Wr); \
    f4 ov = XR[XI]; \
    S0.x = inb0 ? (ov.x + A0.x) : 0.f;  S0.y = inb0 ? (ov.y + A0.y) : 0.f; \
    S1.x = inb1 ? (ov.z + A1.x) : 0.f;  S1.y = inb1 ? (ov.w + A1.y) : 0.f; \
    setc<WPOS>(ob[0], S0.x); setc<WPOS>(ob[1], S0.y); \
    setc<WPOS>(ob[2], S1.x); setc<WPOS>(ob[3], S1.y); \
    { const int _pc = (COL) - 10 < 0 ? 0 : (COL) - 10; \
      XR[XI] = *(const f4*)(o1b + (size_t)_pc * NPAIR + p0x); } \
} while (0)

#define FLUSH(W4) do { \
    if (owned) { \
        *(f4*)(finb + (size_t)(R0 + 0) * WW + (W4)) = ob[0]; \
        *(f4*)(finb + (size_t)(R0 + 1) * WW + (W4)) = ob[1]; \
        *(f4*)(finb + (size_t)(R0 + 2) * WW + (W4)) = ob[2]; \
        *(f4*)(finb + (size_t)(R0 + 3) * WW + (W4)) = ob[3]; \
    } \
} while (0)

        {
            f4 v = *(const f4*)(o1b + (size_t)(WW - 1) * NPAIR + p0x);  // out2[1279] = out1[1279]
            S0.x = inb0 ? v.x : 0.f; S0.y = inb0 ? v.y : 0.f;
            S1.x = inb1 ? v.z : 0.f; S1.y = inb1 ? v.w : 0.f;
            setc<3>(ob[0], S0.x); setc<3>(ob[1], S0.y);
            setc<3>(ob[2], S1.x); setc<3>(ob[3], S1.y);
#pragma unroll
            for (int i = 0; i < 10; ++i)
                XR[i] = *(const f4*)(o1b + (size_t)(1278 - i) * NPAIR + p0x);
        }
#pragma unroll 1
        for (int m = 0; m < 63; ++m) {
            REFRESH();
            const int c0 = 1278 - 20 * m;      // c0 % 4 == 2 always
            STEP2(c0 - 0, 0, 2);
            STEP2(c0 - 1, 1, 1);
            STEP2(c0 - 2, 2, 0);  FLUSH(c0 - 2);
            STEP2(c0 - 3, 3, 3);
            STEP2(c0 - 4, 4, 2);
            STEP2(c0 - 5, 5, 1);
            STEP2(c0 - 6, 6, 0);  FLUSH(c0 - 6);
            STEP2(c0 - 7, 7, 3);
            STEP2(c0 - 8, 8, 2);
            STEP2(c0 - 9, 9, 1);
            STEP2(c0 - 10, 0, 0); FLUSH(c0 - 10);
            STEP2(c0 - 11, 1, 3);
            STEP2(c0 - 12, 2, 2);
            STEP2(c0 - 13, 3, 1);
            STEP2(c0 - 14, 4, 0); FLUSH(c0 - 14);
            STEP2(c0 - 15, 5, 3);
            STEP2(c0 - 16, 6, 2);
            STEP2(c0 - 17, 7, 1);
            STEP2(c0 - 18, 8, 0); FLUSH(c0 - 18);
            STEP2(c0 - 19, 9, 3);
        }
        // tail: cols 18..0 (19 steps, one refresh)
        REFRESH();
        STEP2(18, 0, 2); STEP2(17, 1, 1); STEP2(16, 2, 0); FLUSH(16);
        STEP2(15, 3, 3); STEP2(14, 4, 2); STEP2(13, 5, 1); STEP2(12, 6, 0); FLUSH(12);
        STEP2(11, 7, 3); STEP2(10, 8, 2); STEP2(9, 9, 1);  STEP2(8, 0, 0);  FLUSH(8);
        STEP2(7, 1, 3);  STEP2(6, 2, 2);  STEP2(5, 3, 1);  STEP2(4, 4, 0);  FLUSH(4);
        STEP2(3, 5, 3);  STEP2(2, 6, 2);  STEP2(1, 7, 1);  STEP2(0, 8, 0);  FLUSH(0);
    }
}

extern "C" void kernel_launch(void* const* d_in, const int* in_sizes, int n_in,
                              void* d_out, int out_size, void* d_ws, size_t ws_size,
                              hipStream_t stream) {
    const float* x    = (const float*)d_in[0];
    const float* w_lr = (const float*)d_in[1];
    const float* w_rl = (const float*)d_in[2];

    const size_t half = (size_t)BB * BSTR * sizeof(f2v);   // 62.9 MB
    const bool big = ws_size >= 2 * half;

    f2v*   xq  = (f2v*)d_ws;
    f2v*   o1  = big ? (f2v*)((char*)d_ws + half) : (f2v*)d_out;
    float* fin = big ? (float*)d_out : (float*)d_ws;       // fallback: finals over xq

    scnn_tr<<<dim3(WW / 32, BB), 512, 0, stream>>>(x, xq);
    scnn_scan<<<BB, NT, 0, stream>>>(xq, o1, fin, w_lr, w_rl);
    if (!big) {
        const int n4 = BB * HH * WW / 4;
        scnn_cp<<<2048, 256, 0, stream>>>((const f4*)d_ws, (f4*)d_out, n4);
    }
}